// Round 7
// baseline (536.208 us; speedup 1.0000x reference)
//
#include <hip/hip_runtime.h>
#include <hip/hip_bf16.h>
#include <math.h>

// ModelParallelSoftmaxLoss: loss = mean(logsumexp(x@W^T + b) - (x@W^T+b)[lb])
// N=4096, D=512, V=100000.
// R13: kill the staging gather at the source. R11/R12 both ran at exactly
//      0.42 line-requests/cy/CU (scatter-coalescing wall; request count halved
//      -> time halved). Root cause: W row-major => K-step = 512B-stride gather.
//      (a) prep now writes W_fp8 in K-major FRAGMENT order:
//          out[t*64K + ks*16K + cg*2K + h*1K + (fq*16+fr)*16 + b] =
//          W8[v=t*128+cg*16+fr][d=ks*128+fq*32+h*16+b]  (pure bit-permutation).
//          prep reads stay lane-contiguous; the 4B stores scatter (~16 lines/
//          wave-store, fire-and-forget). Pad slots zero-filled (NaN guard).
//      (b) lse staging = 8 x 1KB lane-contiguous gload_lds (HW fast path,
//          m97-proven); frag read = R11's linear lane*16 layout (measured
//          ZERO bank conflicts; R12's XOR map cost 1.28e7 conflict-cycles).
//      (c) prep grid-strided at 4096 blocks (was 53k blocks single-shot).
//      Unchanged: barrier-free wave-private depth-2 counted pipeline
//      (WAITV(8), lgkmcnt(0) WAR fence), Aa[4][4] regs, log2e folded into x,
//      C=0 first-MFMA, bias in LDS, setprio, bijective XCD swizzle.

#define N_ROWS 4096
#define DIM    512              // elements per row == bytes per row in fp8
#define VOCAB  100000
#define NTILES 782              // ceil(100000/128)
#define VPAD   (NTILES * 128)   // 100096
#define SPLITS 32
#define TPS    25               // ceil(782/32)
#define XELEMS (N_ROWS * DIM)           // 2097152
#define WVALID ((size_t)VOCAB * DIM)    // 51200000
#define WBYTES ((size_t)VPAD * DIM)     // 51249152
#define TILEB  (128 * DIM)              // 65536 B: one 128-col V-tile of W(fp8)
#define PREP_BLOCKS 4096
#define PREP_F4     ((XELEMS + WBYTES) / 4)   // 13,336,576 threads' worth

#define LOG2E 1.44269504088896340736f

typedef __attribute__((ext_vector_type(4))) int   i32x4;
typedef __attribute__((ext_vector_type(8))) int   i32x8;
typedef __attribute__((ext_vector_type(4))) float f32x4;

// ---------------- helpers ----------------

__device__ __forceinline__ void gload_lds16(const char* g, char* l) {
  // async global->LDS, 16B/lane; LDS dest = wave-uniform base + lane*16;
  // global src = PER-LANE address (pass base + lane*16 for contiguous).
  __builtin_amdgcn_global_load_lds(
      (const __attribute__((address_space(1))) unsigned int*)g,
      (__attribute__((address_space(3))) unsigned int*)l, 16, 0, 0);
}

__device__ __forceinline__ int pack4_fp8(float4 f, float sc) {
  int p = __builtin_amdgcn_cvt_pk_fp8_f32(f.x * sc, f.y * sc, 0, false);
  p = __builtin_amdgcn_cvt_pk_fp8_f32(f.z * sc, f.w * sc, p, true);
  return p;
}

// read one 32B fragment stored fragment-order: lo at base, hi at base+1024
__device__ __forceinline__ i32x8 frag32(const char* base) {
  i32x4 lo = *(const i32x4*)(base);
  i32x4 hi = *(const i32x4*)(base + 1024);
  return (i32x8){lo.x, lo.y, lo.z, lo.w, hi.x, hi.y, hi.z, hi.w};
}

// ---------------- prep: cvt x (row-major) + W (K-major fragment tiles) + tgt ----------------

__global__ __launch_bounds__(256) void prep_kernel(const float* __restrict__ x,
                                                   const float* __restrict__ W,
                                                   char* __restrict__ out8,
                                                   const int* __restrict__ lb,
                                                   const float* __restrict__ bias,
                                                   float* __restrict__ tgt) {
  if (blockIdx.x < PREP_BLOCKS) {
    // grid-stride over float4s; lane-contiguous reads each iteration.
    for (size_t i4 = (size_t)blockIdx.x * 256 + threadIdx.x; i4 < (size_t)PREP_F4;
         i4 += (size_t)PREP_BLOCKS * 256) {
      const size_t f0 = i4 * 4;          // float index == out byte index
      if (f0 < (size_t)XELEMS) {
        // x pre-scaled by log2(e), row-major (consumed by lse's Aa reg loads)
        *(int*)(out8 + f0) = pack4_fp8(*(const float4*)(x + f0), LOG2E);
      } else {
        const size_t wf = f0 - XELEMS;   // byte index in the W fp8 image
        int o = 0;
        if (wf < WVALID) o = pack4_fp8(*(const float4*)(W + wf), 32.f);
        // K-major fragment layout (bit-permutation of (v,d)):
        const unsigned v  = (unsigned)(wf >> 9);    // vocab row
        const unsigned dd = (unsigned)(wf & 511);   // byte within row
        const unsigned out = ((v >> 7) << 16)            // tile    * 65536
                           + ((dd >> 7) << 14)           // ks      * 16384
                           + (((v >> 4) & 7u) << 11)     // colgrp  * 2048
                           + (((dd >> 4) & 1u) << 10)    // half    * 1024
                           + (((dd >> 5) & 3u) << 8)     // fq      * 256
                           + ((v & 15u) << 4)            // fr      * 16
                           + (dd & 15u);                 // b
        *(int*)(out8 + XELEMS + out) = o;
      }
    }
  } else {
    // ---- tgt part: 1024 blocks x 4 waves -> 4096 rows; exact fp32 dot
    const int wv = threadIdx.x >> 6;
    const int lane = threadIdx.x & 63;
    const int row = (blockIdx.x - PREP_BLOCKS) * 4 + wv;
    const int t = lb[row];
    const float* xr = x + (size_t)row * DIM;
    const float* wr = W + (size_t)t * DIM;
    float s = 0.f;
#pragma unroll
    for (int i = 0; i < 8; ++i) s += xr[lane + i * 64] * wr[lane + i * 64];
#pragma unroll
    for (int m = 32; m; m >>= 1) s += __shfl_xor(s, m);
    if (lane == 0) tgt[row] = s + bias[t];
  }
}

// ---------------- fused MX-fp8 GEMM + sum-exp ----------------
// grid: 1024 = 32 m-tiles x 32 V-splits. block: 4 waves = 2 row-halves (rh) x
// 2 col-halves (ch). Wave owns 64 rows (4 frags of 16) x 64 cols (4 groups of
// 16). K=128 MFMA, 4 K-steps over D=512.
// A frag (regs, 128 VGPR): lane(fr,fq) = row fr, k-bytes fq*32..+31 per K-window.
// Wave-private B LDS: 2 buffers x 8KB; buffer = ks&1. W image is pre-transposed
// so this wave's (ks, col-half) slab is 8KB CONTIGUOUS in global memory:
//   stage = 8 x gload_lds of 1KB, lane-contiguous (fast path, 16 lines each).
// LDS layout (= R11's, zero conflicts): group gg at gg*2048; frag32 at
// gg*2048 + lane*16 (lo) / +1024 (hi). Depth-2 counted pipeline per wave:
//   K-step u: WAITV(8) [stage(u) landed, stage(u+1) in flight] ->
//   {frag32(gg), 4 MFMA} x4 -> lgkmcnt(0) [WAR] -> stage(u+2).
// Scales: A identity (127, log2e folded into x fp8); B 2^-5 (122).

__global__ __launch_bounds__(256, 2) void lse_kernel(const char* __restrict__ xb,
                                                     const char* __restrict__ wb,
                                                     const float* __restrict__ bias,
                                                     float* __restrict__ spart) {
  __shared__ __align__(16) char ldsB[4][2][8192];   // [wave][buf] 64KB total
  __shared__ float ldsBias[TPS * 128];              // 12.8KB bias (log2e-scaled)

  // Bijective XCD swizzle: one XCD's co-resident blocks cover splits {2x,2x+1}
  // x all 32 m-tiles -> W slices (3.2MB) fit the 4MB per-XCD L2.
  const int d = blockIdx.x;
  const int s     = 2 * (d & 7) + ((d >> 3) & 1) + 16 * (d >> 9);
  const int mtile = (d >> 4) & 31;

  const int m0 = mtile * 128;
  const int t0 = s * TPS;
  const int t1 = (t0 + TPS < NTILES) ? (t0 + TPS) : NTILES;
  const int NT = t1 - t0;                 // 25, or 7 on the last split

  const int tid  = threadIdx.x;
  const int lane = tid & 63;
  const int wv   = tid >> 6;
  const int rh   = wv >> 1;          // row-half (64 rows)
  const int ch   = wv & 1;           // col-half (4 of the 8 col-groups)
  const int fr   = lane & 15;        // frag row (A) / col (B,C)
  const int fq   = lane >> 4;        // frag quad

  // ---- load A fragments into registers (128 VGPRs): 4 row-frags x 4 ksteps ----
  i32x8 Aa[4][4];
  {
    const char* ax = xb + (size_t)(m0 + 64 * rh + fr) * DIM + fq * 32;
#pragma unroll
    for (int rf = 0; rf < 4; ++rf)
#pragma unroll
      for (int ks = 0; ks < 4; ++ks) {
        const char* p = ax + rf * (16 * DIM) + ks * 128;
        i32x4 lo = *(const i32x4*)p;
        i32x4 hi = *(const i32x4*)(p + 16);
        Aa[rf][ks] = (i32x8){lo.x, lo.y, lo.z, lo.w, hi.x, hi.y, hi.z, hi.w};
      }
  }

  // ---- stage this split's bias into LDS ----
  for (int c = tid; c < NT * 128; c += 256) {
    const int col = t0 * 128 + c;
    ldsBias[c] = (col < VOCAB) ? bias[col] * LOG2E : -INFINITY;
  }
  __syncthreads();                                   // bias visible; full drain
  asm volatile("s_waitcnt vmcnt(0)" ::: "memory");   // counted-math clean slate
  __builtin_amdgcn_sched_barrier(0);

  // wave-private staging: this wave's (ks, ch) slab = 8KB contiguous in wb
  char* const myB  = &ldsB[wv][0][0];
  char* const buf0 = myB;
  char* const buf1 = myB + 8192;

  auto stageK = [&](const char* tileSrc, int ks, char* dst) {
    const char* src = tileSrc + ks * 16384 + ch * 8192 + lane * 16;
#pragma unroll
    for (int j = 0; j < 8; ++j)
      gload_lds16(src + j * 1024, dst + j * 1024);
  };

  float S[4][4];
#pragma unroll
  for (int rf = 0; rf < 4; ++rf)
#pragma unroll
    for (int r = 0; r < 4; ++r) S[rf][r] = 0.f;

  f32x4 acc[4][4];   // [row-frag][col-frag]; C=0 at each tile's ks0

// one K-step: wait own stage(u); {read 1 frag (linear lane*16), 4 MFMA} x4;
// WAR-fence; stage(u+2)
#define K_STEP(ksC, FIRSTF, WAITIMM, STAGE_EXPR)                              \
  {                                                                           \
    asm volatile("s_waitcnt vmcnt(" #WAITIMM ")" ::: "memory");               \
    __builtin_amdgcn_sched_barrier(0);                                        \
    const char* fb_ = myB + ((ksC) & 1) * 8192 + lane * 16;                   \
    __builtin_amdgcn_s_setprio(1);                                            \
    _Pragma("unroll")                                                         \
    for (int gg_ = 0; gg_ < 4; ++gg_) {                                       \
      const i32x8 bf_ = frag32(fb_ + gg_ * 2048);                             \
      _Pragma("unroll")                                                       \
      for (int rf_ = 0; rf_ < 4; ++rf_)                                       \
        acc[rf_][gg_] = __builtin_amdgcn_mfma_scale_f32_16x16x128_f8f6f4(     \
            Aa[rf_][ksC], bf_,                                                \
            (FIRSTF) ? (f32x4){0.f, 0.f, 0.f, 0.f} : acc[rf_][gg_],           \
            0, 0, 0, 127, 0, 122);                                            \
    }                                                                         \
    __builtin_amdgcn_s_setprio(0);                                            \
    asm volatile("s_waitcnt lgkmcnt(0)" ::: "memory");                        \
    __builtin_amdgcn_sched_barrier(0);                                        \
    STAGE_EXPR;                                                               \
  }

  auto epilogue = [&](int ti) {
    // C/D (16x16): col = (t0+ti)*128 + 64ch + 16c + fr, row = m0+64rh+16rf+4fq+r
    const float* bT = &ldsBias[ti * 128 + 64 * ch];
    float badd[4];
#pragma unroll
    for (int c = 0; c < 4; ++c) badd[c] = bT[16 * c + fr];
#pragma unroll
    for (int rf = 0; rf < 4; ++rf)
#pragma unroll
      for (int r = 0; r < 4; ++r) {
        float sum = 0.f;
#pragma unroll
        for (int c = 0; c < 4; ++c)
          sum += __builtin_amdgcn_exp2f(acc[rf][c][r] + badd[c]);
        S[rf][r] += sum;
      }
  };

  const char* wt = wb + (size_t)t0 * TILEB;

  // prologue: K-steps 0,1 of tile t0 in flight (16 loads outstanding)
  stageK(wt, 0, buf0);
  stageK(wt, 1, buf1);

  for (int tt = t0; tt < t1 - 1; ++tt, wt += TILEB) {
    K_STEP(0, true,  8, stageK(wt, 2, buf0))
    K_STEP(1, false, 8, stageK(wt, 3, buf1))
    K_STEP(2, false, 8, stageK(wt + TILEB, 0, buf0))
    K_STEP(3, false, 8, stageK(wt + TILEB, 1, buf1))
    epilogue(tt - t0);   // free-running: no barrier; other waves keep pipes fed
  }

  // last tile: no next-tile stages; waits 8,8,8,0
  {
    K_STEP(0, true,  8, stageK(wt, 2, buf0))
    K_STEP(1, false, 8, stageK(wt, 3, buf1))
    K_STEP(2, false, 8, (void)0)
    K_STEP(3, false, 0, (void)0)
    epilogue(NT - 1);
  }
#undef K_STEP

  // ---- cross-wave (col-half) reduction: ch=1 dumps S, ch=0 accumulates ----
  __syncthreads();                       // first barrier since bias; ldsB free
  float* sc = (float*)ldsB;              // stride 20 floats: bank-spread, x4-aligned
  if (ch == 1) {
    float* base = sc + (size_t)(rh * 64 + lane) * 20;
#pragma unroll
    for (int rf = 0; rf < 4; ++rf)
      *(float4*)(base + rf * 4) = (float4){S[rf][0], S[rf][1], S[rf][2], S[rf][3]};
  }
  __syncthreads();
  if (ch == 0) {
    const float* base = sc + (size_t)(rh * 64 + lane) * 20;
#pragma unroll
    for (int rf = 0; rf < 4; ++rf) {
      const float4 v = *(const float4*)(base + rf * 4);
      S[rf][0] += v.x; S[rf][1] += v.y; S[rf][2] += v.z; S[rf][3] += v.w;
    }
    // reduce over the 16 fr-lanes sharing each row, write partials
#pragma unroll
    for (int rf = 0; rf < 4; ++rf)
#pragma unroll
      for (int r = 0; r < 4; ++r) {
        float v = S[rf][r];
        v += __shfl_xor(v, 1);
        v += __shfl_xor(v, 2);
        v += __shfl_xor(v, 4);
        v += __shfl_xor(v, 8);
        if (fr == 0) {
          const int row = m0 + 64 * rh + 16 * rf + 4 * fq + r;
          spart[(size_t)row * SPLITS + s] = v;
        }
      }
  }
}

// ---------------- combine: loss = mean(log(sum_s S_part) - tgt), single block ----------------

__global__ __launch_bounds__(256) void combine_kernel(const float* __restrict__ spart,
                                                      const float* __restrict__ tgt,
                                                      float* __restrict__ out) {
  __shared__ float red[256];
  float local = 0.f;
  for (int r = threadIdx.x; r < N_ROWS; r += 256) {
    const float4* sp = (const float4*)(spart + (size_t)r * SPLITS);
    float st = 0.f;
#pragma unroll
    for (int i = 0; i < 8; ++i) { float4 v = sp[i]; st += (v.x + v.y) + (v.z + v.w); }
    local += __logf(st) - tgt[r];
  }
  red[threadIdx.x] = local;
  __syncthreads();
  for (int step = 128; step; step >>= 1) {
    if (threadIdx.x < step) red[threadIdx.x] += red[threadIdx.x + step];
    __syncthreads();
  }
  if (threadIdx.x == 0) out[0] = red[0] * (1.0f / (float)N_ROWS);
}

// ---------------- launch ----------------
// ws: x_fp8 [4096][512]B @0 | W_fp8 K-major tiles [782][4][8][2][64][16]B |
//     S_part [4096][32] f32 | tgt [4096] f32

extern "C" void kernel_launch(void* const* d_in, const int* in_sizes, int n_in,
                              void* d_out, int out_size, void* d_ws, size_t ws_size,
                              hipStream_t stream) {
  const float* x  = (const float*)d_in[0];
  const int*   lb = (const int*)d_in[1];
  const float* W  = (const float*)d_in[2];
  const float* b  = (const float*)d_in[3];
  float* out = (float*)d_out;

  char* ws = (char*)d_ws;
  const size_t OFF_W   = (size_t)XELEMS;          // 2097152
  const size_t OFF_SP  = OFF_W + WBYTES;          // 53346304
  const size_t OFF_TGT = OFF_SP + (size_t)N_ROWS * SPLITS * 4;
  char*  xb    = ws;
  char*  wb    = ws + OFF_W;
  float* spart = (float*)(ws + OFF_SP);
  float* tgt   = (float*)(ws + OFF_TGT);

  prep_kernel<<<PREP_BLOCKS + 1024, 256, 0, stream>>>(x, W, ws, lb, b, tgt);
  lse_kernel<<<1024, 256, 0, stream>>>(xb, wb, b, spart);
  combine_kernel<<<1, 256, 0, stream>>>(spart, tgt, out);
}